// Round 6
// baseline (1706.419 us; speedup 1.0000x reference)
//
#include <hip/hip_runtime.h>
#include <hip/hip_bf16.h>
#include <hip/hip_fp16.h>
#include <cstddef>
#include <cstdint>

// Problem constants (from reference)
#define Nn 50000
#define Ee 800000
#define Tt 8
#define Ff 128
#define Hh 128
#define Cc 10
#define Gg 64
#define NT 400000    // Tt * Nn

typedef __attribute__((ext_vector_type(8))) short bf16x8;
typedef __attribute__((ext_vector_type(4))) float f32x4;

__device__ inline unsigned short f2bf(float x) {
    __hip_bfloat16 b = __float2bfloat16(x);
    return *reinterpret_cast<unsigned short*>(&b);
}
__device__ inline float bf2f(unsigned short u) {
    __hip_bfloat16 b = *reinterpret_cast<__hip_bfloat16*>(&u);
    return __bfloat162float(b);
}
__device__ inline void split2(float x, unsigned short& h, unsigned short& l) {
    h = f2bf(x);
    l = f2bf(x - bf2f(h));
}

// ---------------------------------------------------------------------------
// Degree / normalization / CSR build
// ---------------------------------------------------------------------------
__global__ __launch_bounds__(256) void count_deg_kernel(const int* __restrict__ dst,
                                                        int* __restrict__ counts) {
    int e = blockIdx.x * 256 + threadIdx.x;
    if (e < Ee) atomicAdd(&counts[dst[e]], 1);
}

__global__ __launch_bounds__(256) void dis_kernel(const int* __restrict__ counts,
                                                  float* __restrict__ dis) {
    int i = blockIdx.x * 256 + threadIdx.x;
    if (i < Nn) dis[i] = 1.0f / sqrtf((float)counts[i] + 1.0f);
}

__global__ __launch_bounds__(256) void scan_block_kernel(const int* __restrict__ counts,
                                                         int* __restrict__ incl,
                                                         int* __restrict__ blksum) {
    __shared__ int s[256];
    int t = threadIdx.x;
    int i = blockIdx.x * 256 + t;
    int v = (i < Nn) ? counts[i] : 0;
    s[t] = v;
    __syncthreads();
    #pragma unroll
    for (int d = 1; d < 256; d <<= 1) {
        int add = (t >= d) ? s[t - d] : 0;
        __syncthreads();
        s[t] += add;
        __syncthreads();
    }
    if (i < Nn) incl[i] = s[t];
    if (t == 255) blksum[blockIdx.x] = s[255];
}

__global__ __launch_bounds__(256) void scan_tops_kernel(int* __restrict__ blksum, int nb) {
    __shared__ int s[256];
    int t = threadIdx.x;
    int v = (t < nb) ? blksum[t] : 0;
    s[t] = v;
    __syncthreads();
    #pragma unroll
    for (int d = 1; d < 256; d <<= 1) {
        int add = (t >= d) ? s[t - d] : 0;
        __syncthreads();
        s[t] += add;
        __syncthreads();
    }
    if (t < nb) blksum[t] = s[t] - v;  // exclusive
}

__global__ __launch_bounds__(256) void scan_fix_kernel(const int* __restrict__ counts,
                                                       const int* __restrict__ incl,
                                                       const int* __restrict__ blksum,
                                                       int* __restrict__ off) {
    int i = blockIdx.x * 256 + threadIdx.x;
    if (i < Nn) off[i] = incl[i] - counts[i] + blksum[i >> 8];
}

__global__ __launch_bounds__(256) void fill_csr_kernel(const int* __restrict__ src,
                                                       const int* __restrict__ dst,
                                                       const float* __restrict__ dis,
                                                       const int* __restrict__ off,
                                                       int* __restrict__ cursor,
                                                       int* __restrict__ csr_src,
                                                       float* __restrict__ csr_w) {
    int e = blockIdx.x * 256 + threadIdx.x;
    if (e >= Ee) return;
    int s = src[e], d = dst[e];
    int slot = off[d] + atomicAdd(&cursor[d], 1);
    csr_src[slot] = s;
    csr_w[slot] = dis[s] * dis[d];
}

// ---------------------------------------------------------------------------
// Weight split kernels (fp32 -> bf16 hi/lo, layout B^T [col][K])
// ---------------------------------------------------------------------------
__global__ __launch_bounds__(256) void wsplit_kernel(const float* __restrict__ W,
                                                     unsigned short* __restrict__ bh,
                                                     unsigned short* __restrict__ bl, int n) {
    int i = blockIdx.x * 256 + threadIdx.x;
    if (i >= n) return;
    unsigned short h, l;
    split2(W[i], h, l);
    bh[i] = h;
    bl[i] = l;
}

__global__ __launch_bounds__(256) void wgcnT_kernel(const float* __restrict__ W,
                                                    unsigned short* __restrict__ bh,
                                                    unsigned short* __restrict__ bl) {
    int i = blockIdx.x * 256 + threadIdx.x;
    if (i >= 128 * 128) return;
    int f = i >> 7, hc = i & 127;
    unsigned short h, l;
    split2(W[i], h, l);
    bh[hc * 128 + f] = h;
    bl[hc * 128 + f] = l;
}

// ---------------------------------------------------------------------------
// xw GEMM: xwp[(n*8+t)][128] = x_seq[(t*Nn+n)][128] @ W_gcn, split-bf16 MFMA.
// ---------------------------------------------------------------------------
__global__ __launch_bounds__(256) void xw_gemm(const float* __restrict__ X,
                                               const unsigned short* __restrict__ BTh,
                                               const unsigned short* __restrict__ BTl,
                                               float* __restrict__ Cout) {
    __shared__ __align__(16) char lds[32768];
    char* pAh = lds;
    char* pAl = lds + 16384;
    const int bm = blockIdx.x * 128;
    const int tid = threadIdx.x;
    const int wid = tid >> 6, lane = tid & 63;
    const int wr = wid >> 1, wc = wid & 1;
    const int l15 = lane & 15, l4 = lane >> 4;

    f32x4 acc[4][4] = {};

    for (int kh = 0; kh < 2; ++kh) {
        if (kh) __syncthreads();
        #pragma unroll
        for (int i = 0; i < 8; ++i) {
            int idx = tid + i * 256;
            int row = idx >> 4;
            int k4 = idx & 15;
            float4 v = *(const float4*)(X + (size_t)(bm + row) * 128 + kh * 64 + k4 * 4);
            ushort4 h, l;
            split2(v.x, h.x, l.x);
            split2(v.y, h.y, l.y);
            split2(v.z, h.z, l.z);
            split2(v.w, h.w, l.w);
            int off = row * 128 + ((k4 * 8) ^ ((row & 7) << 4));
            *(ushort4*)(pAh + off) = h;
            *(ushort4*)(pAl + off) = l;
        }
        __syncthreads();

        #pragma unroll
        for (int kq = 0; kq < 2; ++kq) {
            bf16x8 a_h[4], a_l[4], b_h[4], b_l[4];
            const int kbase = kq * 64 + l4 * 16;
            #pragma unroll
            for (int m = 0; m < 4; ++m) {
                const int r = wr * 64 + m * 16 + l15;
                const int byteo = r * 128 + (kbase ^ ((r & 7) << 4));
                a_h[m] = *(const bf16x8*)(pAh + byteo);
                a_l[m] = *(const bf16x8*)(pAl + byteo);
            }
            #pragma unroll
            for (int n = 0; n < 4; ++n) {
                const int col = wc * 64 + n * 16 + l15;
                const size_t bo = (size_t)col * 128 + kh * 64 + kq * 32 + l4 * 8;
                b_h[n] = *(const bf16x8*)(BTh + bo);
                b_l[n] = *(const bf16x8*)(BTl + bo);
            }
            #pragma unroll
            for (int m = 0; m < 4; ++m)
                #pragma unroll
                for (int n = 0; n < 4; ++n) {
                    acc[m][n] = __builtin_amdgcn_mfma_f32_16x16x32_bf16(a_h[m], b_h[n],
                                                                        acc[m][n], 0, 0, 0);
                    acc[m][n] = __builtin_amdgcn_mfma_f32_16x16x32_bf16(a_h[m], b_l[n],
                                                                        acc[m][n], 0, 0, 0);
                    acc[m][n] = __builtin_amdgcn_mfma_f32_16x16x32_bf16(a_l[m], b_h[n],
                                                                        acc[m][n], 0, 0, 0);
                }
        }
    }

    // epilogue: remap GEMM row r = t*Nn + n  ->  output row n*8 + t
    #pragma unroll
    for (int m = 0; m < 4; ++m) {
        const int row = bm + wr * 64 + m * 16 + l4 * 4;
        #pragma unroll
        for (int q = 0; q < 4; ++q) {
            const int r = row + q;
            const int tt = r / Nn;
            const int nn = r - tt * Nn;
            float* outrow = Cout + ((size_t)nn * 8 + tt) * 128;
            #pragma unroll
            for (int n = 0; n < 4; ++n) {
                const int col = wc * 64 + n * 16 + l15;
                outrow[col] = acc[m][n][q];
            }
        }
    }
}

// ---------------------------------------------------------------------------
// FUSED aggregation + gx GEMM. One block = 8 nodes = 64 rows [(n*8+t)].
// Phase A: per wave, 2 nodes; gather xwp 4KB blocks (shfl-broadcast indices,
//          depth-2 payload pipeline); relu+bias; write gcn bf16 hi/lo into
//          LDS (XOR-swizzled). gcn never touches global memory.
// Phase B: gx[64x384] = gcn @ W_ih^T + b_ih (split-bf16 MFMA, 288 MFMA),
//          each wave owns 96 cols; output fp16 to gx16 rows blockIdx*64+row.
// ---------------------------------------------------------------------------
__global__ __launch_bounds__(256) void aggx_kernel(const float* __restrict__ xwp,
                                                   const float* __restrict__ dis,
                                                   const int* __restrict__ off,
                                                   const int* __restrict__ counts,
                                                   const int* __restrict__ csr_src,
                                                   const float* __restrict__ csr_w,
                                                   const float* __restrict__ b_gcn,
                                                   const unsigned short* __restrict__ BTh,
                                                   const unsigned short* __restrict__ BTl,
                                                   const float* __restrict__ bias,
                                                   __half* __restrict__ gx16) {
    __shared__ __align__(16) char lds[32768];  // hA hi 16KB + lo 16KB
    char* pAh = lds;
    char* pAl = lds + 16384;
    const int n0 = blockIdx.x * 8;
    const int tid = threadIdx.x;
    const int wid = tid >> 6, lane = tid & 63;
    const int l15 = lane & 15, l4 = lane >> 4;

    // ---- Phase A: aggregate 2 nodes per wave ----
    for (int nl = 0; nl < 2; ++nl) {
        const int n = n0 + wid * 2 + nl;
        const float dv = dis[n];
        const float dsq = dv * dv;
        const float* bn_ = xwp + (size_t)n * 1024 + lane * 4;
        f32x4 acc[4];
        #pragma unroll
        for (int p = 0; p < 4; ++p) acc[p] = (*(const f32x4*)(bn_ + p * 256)) * dsq;

        const int s0 = off[n];
        const int cnt = counts[n];
        for (int base = 0; base < cnt; base += 64) {
            const int m = min(64, cnt - base);
            int idxv = 0;
            float wvv = 0.f;
            {
                int j = base + lane;
                if (j < cnt) {
                    idxv = csr_src[s0 + j];
                    wvv = csr_w[s0 + j];
                }
            }
            // depth-2 pipeline
            int sA = __shfl(idxv, 0);
            float wA = __shfl(wvv, 0);
            const float* pA = xwp + (size_t)sA * 1024 + lane * 4;
            f32x4 v0 = *(const f32x4*)(pA);
            f32x4 v1 = *(const f32x4*)(pA + 256);
            f32x4 v2 = *(const f32x4*)(pA + 512);
            f32x4 v3 = *(const f32x4*)(pA + 768);
            for (int k = 0; k < m; ++k) {
                f32x4 u0 = v0, u1 = v1, u2 = v2, u3 = v3;
                const float w = wA;
                if (k + 1 < m) {
                    sA = __shfl(idxv, k + 1);
                    wA = __shfl(wvv, k + 1);
                    const float* pN = xwp + (size_t)sA * 1024 + lane * 4;
                    v0 = *(const f32x4*)(pN);
                    v1 = *(const f32x4*)(pN + 256);
                    v2 = *(const f32x4*)(pN + 512);
                    v3 = *(const f32x4*)(pN + 768);
                }
                acc[0] += u0 * w;
                acc[1] += u1 * w;
                acc[2] += u2 * w;
                acc[3] += u3 * w;
            }
        }

        // relu + bias, split, write into LDS hA (swizzled)
        #pragma unroll
        for (int p = 0; p < 4; ++p) {
            const int q = p * 1024 + lane * 16;  // byte in node's 4KB block
            const int t = q >> 9;
            const int c0 = (q & 511) >> 2;       // float col (mult of 4)
            float4 bb = *(const float4*)(b_gcn + c0);
            float w0 = fmaxf(acc[p][0] + bb.x, 0.f);
            float w1 = fmaxf(acc[p][1] + bb.y, 0.f);
            float w2 = fmaxf(acc[p][2] + bb.z, 0.f);
            float w3 = fmaxf(acc[p][3] + bb.w, 0.f);
            ushort4 oh, ol;
            split2(w0, oh.x, ol.x);
            split2(w1, oh.y, ol.y);
            split2(w2, oh.z, ol.z);
            split2(w3, oh.w, ol.w);
            const int r = (wid * 2 + nl) * 8 + t;        // local row, r&7 == t
            const int byteo = r * 256 + ((c0 * 2) ^ (t << 4));
            *(ushort4*)(pAh + byteo) = oh;
            *(ushort4*)(pAl + byteo) = ol;
        }
    }
    __syncthreads();

    // ---- Phase B: gx = gcn @ W_ih^T + b_ih, wave owns 96 cols ----
    f32x4 acc[4][6] = {};
    const int wc0 = wid * 96;
    #pragma unroll
    for (int kq = 0; kq < 4; ++kq) {
        bf16x8 a_h[4], a_l[4];
        const int kbase = kq * 64 + l4 * 16;
        #pragma unroll
        for (int m = 0; m < 4; ++m) {
            const int r = m * 16 + l15;
            const int byteo = r * 256 + (kbase ^ ((r & 7) << 4));
            a_h[m] = *(const bf16x8*)(pAh + byteo);
            a_l[m] = *(const bf16x8*)(pAl + byteo);
        }
        #pragma unroll
        for (int n = 0; n < 6; ++n) {
            const int col = wc0 + n * 16 + l15;
            const size_t bo = (size_t)col * 128 + kq * 32 + l4 * 8;
            bf16x8 b_h = *(const bf16x8*)(BTh + bo);
            bf16x8 b_l = *(const bf16x8*)(BTl + bo);
            #pragma unroll
            for (int m = 0; m < 4; ++m) {
                acc[m][n] = __builtin_amdgcn_mfma_f32_16x16x32_bf16(a_h[m], b_h,
                                                                    acc[m][n], 0, 0, 0);
                acc[m][n] = __builtin_amdgcn_mfma_f32_16x16x32_bf16(a_h[m], b_l,
                                                                    acc[m][n], 0, 0, 0);
                acc[m][n] = __builtin_amdgcn_mfma_f32_16x16x32_bf16(a_l[m], b_h,
                                                                    acc[m][n], 0, 0, 0);
            }
        }
    }

    #pragma unroll
    for (int n = 0; n < 6; ++n) {
        const int col = wc0 + n * 16 + l15;
        const float bb = bias[col];
        #pragma unroll
        for (int m = 0; m < 4; ++m) {
            const int row = blockIdx.x * 64 + m * 16 + l4 * 4;
            #pragma unroll
            for (int q = 0; q < 4; ++q)
                gx16[(size_t)(row + q) * 384 + col] = __float2half(acc[m][n][q] + bb);
        }
    }
}

// ---------------------------------------------------------------------------
// Single-launch fused GRU: block owns 64 rows; h lives in registers (32/thread)
// for all 8 steps. LDS time-aliased: hA (32KB, MFMA A-operand) <-> ghT (49.5KB).
// Per step t>=1: [write hA from h regs] [MFMA gh = h @ W_hh^T] [ghT transpose]
// [gate: h = (1-z)*n + z*h]. t=0 shortcut: gh = b_hh only.
// ---------------------------------------------------------------------------
__global__ __launch_bounds__(256) void gru_kernel(const unsigned short* __restrict__ BTh,
                                                  const unsigned short* __restrict__ BTl,
                                                  const __half* __restrict__ gx,
                                                  const float* __restrict__ b_hh,
                                                  float* __restrict__ hbuf) {
    __shared__ __align__(16) char lds[50688];  // hA (32KB) and ghT (49.5KB) time-aliased
    char* pAh = lds;
    char* pAl = lds + 16384;
    const int r0 = blockIdx.x * 64;
    const int tid = threadIdx.x;
    const int wid = tid >> 6, lane = tid & 63;
    const int l15 = lane & 15, l4 = lane >> 4;
    const int c = tid & 127;
    const int rpb = (tid >> 7) * 16;
    const float bhr = b_hh[c], bhz = b_hh[c + 128], bhn = b_hh[c + 256];

    float h[32];  // h[(rp-rpb)*2+rr] = h[r0 + rp*2 + rr][c]

    // ---- t = 0: gh = b_hh, h_old = 0 ----
    #pragma unroll
    for (int it = 0; it < 16; ++it) {
        #pragma unroll
        for (int rr = 0; rr < 2; ++rr) {
            const int row = r0 + (rpb + it) * 2 + rr;
            float hv = 0.f;
            if (row < Nn) {
                const size_t gxb = (size_t)row * 8 * 384;  // t = 0
                float xr = __half2float(gx[gxb + c]);
                float xz = __half2float(gx[gxb + c + 128]);
                float xn = __half2float(gx[gxb + c + 256]);
                float rg = 1.f / (1.f + expf(-(xr + bhr)));
                float zg = 1.f / (1.f + expf(-(xz + bhz)));
                float ng = tanhf(xn + rg * bhn);
                hv = (1.f - zg) * ng;
            }
            h[it * 2 + rr] = hv;
        }
    }

    for (int t = 1; t < Tt; ++t) {
        __syncthreads();  // prev gate's ghT reads done before hA overwrite
        // ---- write h regs -> hA (bf16 hi/lo, swizzled) ----
        #pragma unroll
        for (int it = 0; it < 16; ++it) {
            #pragma unroll
            for (int rr = 0; rr < 2; ++rr) {
                const int lr = (rpb + it) * 2 + rr;  // local row 0..63
                unsigned short sh, sl;
                split2(h[it * 2 + rr], sh, sl);
                const int byteo = lr * 256 + ((2 * c) ^ ((lr & 7) << 4));
                *(unsigned short*)(pAh + byteo) = sh;
                *(unsigned short*)(pAl + byteo) = sl;
            }
        }
        __syncthreads();

        // ---- MFMA: gh tile, wave owns 96 cols ----
        f32x4 acc[4][6] = {};
        const int wc0 = wid * 96;
        #pragma unroll
        for (int kq = 0; kq < 4; ++kq) {
            bf16x8 a_h[4], a_l[4];
            const int kbase = kq * 64 + l4 * 16;
            #pragma unroll
            for (int m = 0; m < 4; ++m) {
                const int r = m * 16 + l15;
                const int byteo = r * 256 + (kbase ^ ((r & 7) << 4));
                a_h[m] = *(const bf16x8*)(pAh + byteo);
                a_l[m] = *(const bf16x8*)(pAl + byteo);
            }
            #pragma unroll
            for (int n = 0; n < 6; ++n) {
                const int col = wc0 + n * 16 + l15;
                const size_t bo = (size_t)col * 128 + kq * 32 + l4 * 8;
                bf16x8 b_h = *(const bf16x8*)(BTh + bo);
                bf16x8 b_l = *(const bf16x8*)(BTl + bo);
                #pragma unroll
                for (int m = 0; m < 4; ++m) {
                    acc[m][n] = __builtin_amdgcn_mfma_f32_16x16x32_bf16(a_h[m], b_h,
                                                                        acc[m][n], 0, 0, 0);
                    acc[m][n] = __builtin_amdgcn_mfma_f32_16x16x32_bf16(a_h[m], b_l,
                                                                        acc[m][n], 0, 0, 0);
                    acc[m][n] = __builtin_amdgcn_mfma_f32_16x16x32_bf16(a_l[m], b_h,
                                                                        acc[m][n], 0, 0, 0);
                }
            }
        }
        __syncthreads();  // all hA reads done before ghT overwrites the region

        // ---- ghT: fp16 transposed [col][132B] ----
        #pragma unroll
        for (int m = 0; m < 4; ++m)
            #pragma unroll
            for (int n = 0; n < 6; ++n) {
                const int col = wc0 + n * 16 + l15;
                const int rw = m * 16 + l4 * 4;
                __half2 p0, p1;
                p0.x = __float2half(acc[m][n][0]);
                p0.y = __float2half(acc[m][n][1]);
                p1.x = __float2half(acc[m][n][2]);
                p1.y = __float2half(acc[m][n][3]);
                *(__half2*)(lds + col * 132 + rw * 2) = p0;
                *(__half2*)(lds + col * 132 + rw * 2 + 4) = p1;
            }
        __syncthreads();

        // ---- gate ----
        #pragma unroll
        for (int it = 0; it < 16; ++it) {
            const int rp = rpb + it;
            __half2 vr = *(const __half2*)(lds + c * 132 + rp * 4);
            __half2 vz = *(const __half2*)(lds + (c + 128) * 132 + rp * 4);
            __half2 vn = *(const __half2*)(lds + (c + 256) * 132 + rp * 4);
            const float ghr[2] = {__half2float(vr.x), __half2float(vr.y)};
            const float ghz[2] = {__half2float(vz.x), __half2float(vz.y)};
            const float ghn[2] = {__half2float(vn.x), __half2float(vn.y)};
            #pragma unroll
            for (int rr = 0; rr < 2; ++rr) {
                const int row = r0 + rp * 2 + rr;
                if (row >= Nn) continue;
                const size_t gxb = ((size_t)row * 8 + t) * 384;
                float xr = __half2float(gx[gxb + c]);
                float xz = __half2float(gx[gxb + c + 128]);
                float xn = __half2float(gx[gxb + c + 256]);
                float rg = 1.f / (1.f + expf(-(xr + ghr[rr] + bhr)));
                float zg = 1.f / (1.f + expf(-(xz + ghz[rr] + bhz)));
                float ng = tanhf(xn + rg * (ghn[rr] + bhn));
                const int hi = it * 2 + rr;
                h[hi] = (1.f - zg) * ng + zg * h[hi];
            }
        }
    }

    // ---- write final h ----
    #pragma unroll
    for (int it = 0; it < 16; ++it) {
        #pragma unroll
        for (int rr = 0; rr < 2; ++rr) {
            const int row = r0 + (rpb + it) * 2 + rr;
            if (row < Nn) hbuf[(size_t)row * 128 + c] = h[it * 2 + rr];
        }
    }
}

// ---------------------------------------------------------------------------
// Graph sizes by binary search on the SORTED batch array
// ---------------------------------------------------------------------------
__global__ void gcount_bs_kernel(const int* __restrict__ batch, float* __restrict__ ginv) {
    int g = threadIdx.x;
    if (g >= Gg) return;
    int lo = 0, hi = Nn;
    while (lo < hi) {
        int m = (lo + hi) >> 1;
        if (batch[m] < g) lo = m + 1; else hi = m;
    }
    int start = lo;
    lo = 0; hi = Nn;
    while (lo < hi) {
        int m = (lo + hi) >> 1;
        if (batch[m] <= g) lo = m + 1; else hi = m;
    }
    ginv[g] = 1.f / fmaxf((float)(lo - start), 1.f);
}

// ---------------------------------------------------------------------------
// FC (h @ W_fc + b_fc) fused with mean pooling via atomics
// ---------------------------------------------------------------------------
__global__ __launch_bounds__(256) void fc_pool_kernel(const float* __restrict__ h,
                                                      const float* __restrict__ Wfc,
                                                      const float* __restrict__ bfc,
                                                      const int* __restrict__ batch,
                                                      const float* __restrict__ ginv,
                                                      float* __restrict__ out) {
    __shared__ float hs[16][128];
    __shared__ float wf[128][10];
    __shared__ float bf[10];
    int b0 = blockIdx.x * 16;
    int t = threadIdx.x;
    for (int i = t; i < 128 * 10; i += 256) wf[i / 10][i % 10] = Wfc[i];
    if (t < 10) bf[t] = bfc[t];
    for (int i = t; i < 16 * 32; i += 256) {
        int r = i >> 5, c4 = i & 31;
        int row = b0 + r;
        float4 v = make_float4(0.f, 0.f, 0.f, 0.f);
        if (row < Nn) v = *(const float4*)(h + (size_t)row * 128 + c4 * 4);
        *(float4*)(&hs[r][c4 * 4]) = v;
    }
    __syncthreads();
    if (t < 160) {
        int r = t / 10, c = t % 10;
        int row = b0 + r;
        if (row < Nn) {
            float acc = bf[c];
            #pragma unroll
            for (int k = 0; k < 128; ++k) acc = fmaf(hs[r][k], wf[k][c], acc);
            int g = batch[row];
            atomicAdd(out + g * 10 + c, acc * ginv[g]);
        }
    }
}

// ---------------------------------------------------------------------------
// Launch
// ---------------------------------------------------------------------------
extern "C" void kernel_launch(void* const* d_in, const int* in_sizes, int n_in,
                              void* d_out, int out_size, void* d_ws, size_t ws_size,
                              hipStream_t stream) {
    const float* x_seq = (const float*)d_in[0];
    const int*   eidx  = (const int*)d_in[1];
    const int*   batch = (const int*)d_in[2];
    const float* W_gcn = (const float*)d_in[3];
    const float* b_gcn = (const float*)d_in[4];
    const float* W_ih  = (const float*)d_in[5];
    const float* W_hh  = (const float*)d_in[6];
    const float* b_ih  = (const float*)d_in[7];
    const float* b_hh  = (const float*)d_in[8];
    const float* W_fc  = (const float*)d_in[9];
    const float* b_fc  = (const float*)d_in[10];
    const int* src = eidx;
    const int* dst = eidx + Ee;
    float* out = (float*)d_out;

    size_t woff = 0;
    auto alloc = [&](size_t bytes) -> void* {
        void* p = (char*)d_ws + woff;
        woff = (woff + bytes + 255) & ~(size_t)255;
        return p;
    };
    int*   counts  = (int*)alloc(Nn * 4);
    int*   cursor  = (int*)alloc(Nn * 4);
    int*   incl    = (int*)alloc(Nn * 4);
    int*   blksum  = (int*)alloc(256 * 4);
    int*   offx    = (int*)alloc(Nn * 4);
    int*   csr_src = (int*)alloc(Ee * 4);
    float* csr_w   = (float*)alloc(Ee * 4);
    float* dis     = (float*)alloc(Nn * 4);
    unsigned short* wg_hi  = (unsigned short*)alloc(128 * 128 * 2);
    unsigned short* wg_lo  = (unsigned short*)alloc(128 * 128 * 2);
    unsigned short* wih_hi = (unsigned short*)alloc(384 * 128 * 2);
    unsigned short* wih_lo = (unsigned short*)alloc(384 * 128 * 2);
    unsigned short* whh_hi = (unsigned short*)alloc(384 * 128 * 2);
    unsigned short* whh_lo = (unsigned short*)alloc(384 * 128 * 2);
    float* ginv = (float*)alloc(256);
    float* xwp   = (float*)alloc((size_t)NT * 128 * 4);   // 204.8 MB, [n][t][128]
    __half* gx16 = (__half*)alloc((size_t)NT * 384 * 2);  // 307.2 MB, [(n*8+t)][384]
    float* hbuf  = (float*)alloc((size_t)Nn * 128 * 4);   // 25.6 MB
    // total ~ 550 MB < 819.2 MB ws

    hipMemsetAsync(counts, 0, Nn * 4, stream);
    hipMemsetAsync(cursor, 0, Nn * 4, stream);
    hipMemsetAsync(d_out, 0, (size_t)Gg * Cc * 4, stream);

    const int nbN = (Nn + 255) / 256;
    const int nbE = (Ee + 255) / 256;

    count_deg_kernel<<<nbE, 256, 0, stream>>>(dst, counts);
    dis_kernel<<<nbN, 256, 0, stream>>>(counts, dis);
    scan_block_kernel<<<nbN, 256, 0, stream>>>(counts, incl, blksum);
    scan_tops_kernel<<<1, 256, 0, stream>>>(blksum, nbN);
    scan_fix_kernel<<<nbN, 256, 0, stream>>>(counts, incl, blksum, offx);
    fill_csr_kernel<<<nbE, 256, 0, stream>>>(src, dst, dis, offx, cursor, csr_src, csr_w);

    wsplit_kernel<<<(384 * 128 + 255) / 256, 256, 0, stream>>>(W_ih, wih_hi, wih_lo, 384 * 128);
    wsplit_kernel<<<(384 * 128 + 255) / 256, 256, 0, stream>>>(W_hh, whh_hi, whh_lo, 384 * 128);
    wgcnT_kernel<<<(128 * 128 + 255) / 256, 256, 0, stream>>>(W_gcn, wg_hi, wg_lo);
    gcount_bs_kernel<<<1, 64, 0, stream>>>(batch, ginv);

    // xw for all T, output [n][t][128]
    xw_gemm<<<NT / 128, 256, 0, stream>>>(x_seq, wg_hi, wg_lo, xwp);
    // fused aggregation + gx GEMM (gcn stays in LDS)
    aggx_kernel<<<Nn / 8, 256, 0, stream>>>(xwp, dis, offx, counts, csr_src, csr_w,
                                            b_gcn, wih_hi, wih_lo, b_ih, gx16);
    // single-launch GRU over all 8 steps, h in registers
    gru_kernel<<<(Nn + 63) / 64, 256, 0, stream>>>(whh_hi, whh_lo, gx16, b_hh, hbuf);

    fc_pool_kernel<<<(Nn + 15) / 16, 256, 0, stream>>>(hbuf, W_fc, b_fc, batch, ginv, out);
}